// Round 6
// baseline (704.400 us; speedup 1.0000x reference)
//
#include <hip/hip_runtime.h>
#include <math.h>

#define BLOCK 256
#define LBv 1e-20f
#define UBv 1e20f

// Literal transcription of the reference _forward, one thread per direction.
// OUTPUT IS FLOAT32 (harness doc: out dtype = reference output dtype = f32).
// R2/R4/R5 wrote bf16 -> read back as f32 gave a decimated copy -> error 19 > 12.
__global__ __launch_bounds__(BLOCK) void mcnet_literal(
    const float* __restrict__ verts,   // (NT, V, 3) f32
    const float* __restrict__ smooth,  // (NT,)      f32
    const float* __restrict__ dirs,    // (D, 3)     f32
    float* __restrict__ out,
    int NT, int V, int D, int SPLIT,
    size_t offDH, size_t offMV, size_t offDIR, size_t offLV, size_t offZ)
{
    extern __shared__ float smem[];            // [4*V] lv (float4) + [3*BLOCK] reduce
    float4* lv = (float4*)smem;
    float*  red = smem + 4 * (size_t)V;

    const int tid  = threadIdx.x;
    const int tile = blockIdx.x / SPLIT;
    const int s    = blockIdx.x % SPLIT;

    // ---- mean via plain LDS tree reduction ----
    float sx = 0.f, sy = 0.f, sz = 0.f;
    for (int v = tid; v < V; v += BLOCK) {
        const float* vp = verts + ((size_t)tile * V + v) * 3;
        sx += vp[0]; sy += vp[1]; sz += vp[2];
    }
    red[tid] = sx; red[tid + BLOCK] = sy; red[tid + 2 * BLOCK] = sz;
    __syncthreads();
    for (int st = BLOCK / 2; st > 0; st >>= 1) {
        if (tid < st) {
            red[tid]             += red[tid + st];
            red[tid + BLOCK]     += red[tid + BLOCK + st];
            red[tid + 2 * BLOCK] += red[tid + 2 * BLOCK + st];
        }
        __syncthreads();
    }
    const float inv = 1.0f / (float)V;
    const float mx = red[0] * inv, my = red[BLOCK] * inv, mz = red[2 * BLOCK] * inv;

    for (int v = tid; v < V; v += BLOCK) {
        const float* vp = verts + ((size_t)tile * V + v) * 3;
        lv[v] = make_float4(vp[0] - mx, vp[1] - my, vp[2] - mz, 0.f);
    }
    __syncthreads();

    // ---- small outputs ----
    if (s == 0) {
        for (int v = tid; v < V; v += BLOCK) {
            float4 q = lv[v];
            size_t o = offLV + ((size_t)tile * V + v) * 3;
            out[o + 0] = q.x;
            out[o + 1] = q.y;
            out[o + 2] = q.z;
        }
        if (tid == 0) {
            size_t mo = offMV + (size_t)tile * 3;
            out[mo + 0] = mx;
            out[mo + 1] = my;
            out[mo + 2] = mz;
        }
    }
    if (blockIdx.x == 0) {
        for (int i = tid; i < D * 3; i += BLOCK)
            out[offDIR + i] = dirs[i];
        if (tid < 2) out[offZ + tid] = 0.f;
    }

    const int d = s * BLOCK + tid;
    if (d >= D) return;

    const float dx = dirs[d * 3 + 0];
    const float dy = dirs[d * 3 + 1];
    const float dz = dirs[d * 3 + 2];
    const float pv = smooth[tile];

    // zm_log = max_v log10(zm) (zm>0) else -inf; log10 monotone -> use zmax
    float zmax = 0.f;
    for (int v = 0; v < V; ++v) {
        float4 q = lv[v];
        float z = q.x * dx + q.y * dy + q.z * dz;
        zmax = fmaxf(zmax, z);
    }
    float zm_log   = (zmax > 0.f) ? log10f(zmax) : -INFINITY;
    float exponent = zm_log * pv;
    float lk = (exponent < -20.f) ? (-20.f - exponent) / pv : 0.f;
    float kk = powf(10.f, fminf(fmaxf(ceilf(lk), 0.f), UBv));

    // sum_zm_p = sum_v where(zms>0, clip(zms^p, LB, UB), 0)
    float sum = 0.f;
    for (int v = 0; v < V; ++v) {
        float4 q = lv[v];
        float z   = q.x * dx + q.y * dy + q.z * dz;
        float zms = fmaxf(z, 0.f) * kk;
        float w   = (zms > 0.f) ? fminf(fmaxf(powf(zms, pv), LBv), UBv) : 0.f;
        sum += w;
    }
    float h = fminf(fmaxf(powf(sum, 1.f / pv), LBv), UBv);

    // surf = sum_v dhdz * lv + mean; dhdz = where(ratio>0, clip(ratio^(p-1),LB,UB), LB)
    float ax = 0.f, ay = 0.f, az = 0.f;
    const float pm1 = pv - 1.f;
    for (int v = 0; v < V; ++v) {
        float4 q = lv[v];
        float z     = q.x * dx + q.y * dy + q.z * dz;
        float zms   = fmaxf(z, 0.f) * kk;
        float ratio = zms / h;
        float w = (ratio > 0.f) ? fminf(fmaxf(powf(ratio, pm1), LBv), UBv) : LBv;
        ax += w * q.x; ay += w * q.y; az += w * q.z;
    }

    size_t po = ((size_t)tile * D + d) * 3;
    out[po + 0] = ax + mx;
    out[po + 1] = ay + my;
    out[po + 2] = az + mz;

    float hout = h / kk;
    size_t dho = offDH + ((size_t)tile * D + d) * 4;
    out[dho + 0] = dx;
    out[dho + 1] = dy;
    out[dho + 2] = dz;
    out[dho + 3] = hout;
}

extern "C" void kernel_launch(void* const* d_in, const int* in_sizes, int n_in,
                              void* d_out, int out_size, void* d_ws, size_t ws_size,
                              hipStream_t stream) {
    const float* verts  = (const float*)d_in[0];
    const float* smooth = (const float*)d_in[1];
    const float* dirs   = (const float*)d_in[2];
    float* out = (float*)d_out;

    // verts = NT*V*3, smooth = NT, dirs = D*3
    const int NT = in_sizes[1];
    const int D  = in_sizes[2] / 3;
    const int V  = in_sizes[0] / (3 * NT);
    const int SPLIT = (D + BLOCK - 1) / BLOCK;

    const size_t offDH  = (size_t)NT * D * 3;            // after points
    const size_t offMV  = offDH  + (size_t)NT * D * 4;   // after direction_h
    const size_t offDIR = offMV  + (size_t)NT * 3;       // after mean_v
    const size_t offLV  = offDIR + (size_t)D * 3;        // after directions
    const size_t offZ   = offLV  + (size_t)NT * V * 3;   // after local_vertices

    const size_t shmem = (4 * (size_t)V + 3 * BLOCK) * sizeof(float);

    dim3 grid(NT * SPLIT);
    dim3 block(BLOCK);
    hipLaunchKernelGGL(mcnet_literal, grid, block, shmem, stream,
                       verts, smooth, dirs, out,
                       NT, V, D, SPLIT, offDH, offMV, offDIR, offLV, offZ);
}

// Round 7
// 116.182 us; speedup vs baseline: 6.0629x; 6.0629x over previous
//
#include <hip/hip_runtime.h>
#include <math.h>

#define BLOCK 256
#define LBv 1e-20f
#define UBv 1e20f
#define LOG2_10 3.321928094887362f
#define LOG10_2 0.3010299956639812f

// Raw HW transcendentals: v_log_f32 / v_exp_f32 (~1 ulp).
// Edge semantics used: log2(0)=-inf, log2(neg)=NaN, exp2(-inf)=0 — all lanes
// relying on these are masked by explicit (z>0) selects below.
#if __has_builtin(__builtin_amdgcn_logf) && __has_builtin(__builtin_amdgcn_exp2f)
__device__ __forceinline__ float fast_log2(float x) { return __builtin_amdgcn_logf(x); }
__device__ __forceinline__ float fast_exp2(float x) { return __builtin_amdgcn_exp2f(x); }
#else
__device__ __forceinline__ float fast_log2(float x) { return log2f(x); }
__device__ __forceinline__ float fast_exp2(float x) { return exp2f(x); }
#endif

__global__ __launch_bounds__(BLOCK) void mcnet_fast(
    const float* __restrict__ verts,   // (NT, V, 3) f32
    const float* __restrict__ smooth,  // (NT,)      f32
    const float* __restrict__ dirs,    // (D, 3)     f32
    float* __restrict__ out,           // f32, chunks concatenated flat
    int NT, int V, int D, int SPLIT,
    size_t offDH, size_t offMV, size_t offDIR, size_t offLV, size_t offZ)
{
    extern __shared__ float smem[];            // [4*V] lv (float4) + [3*BLOCK] reduce
    float4* lv = (float4*)smem;
    float*  red = smem + 4 * (size_t)V;

    const int tid  = threadIdx.x;
    const int tile = blockIdx.x / SPLIT;
    const int s    = blockIdx.x % SPLIT;

    // ---- mean via LDS tree reduction (once per block; negligible cost) ----
    float sx = 0.f, sy = 0.f, sz = 0.f;
    for (int v = tid; v < V; v += BLOCK) {
        const float* vp = verts + ((size_t)tile * V + v) * 3;
        sx += vp[0]; sy += vp[1]; sz += vp[2];
    }
    red[tid] = sx; red[tid + BLOCK] = sy; red[tid + 2 * BLOCK] = sz;
    __syncthreads();
    for (int st = BLOCK / 2; st > 0; st >>= 1) {
        if (tid < st) {
            red[tid]             += red[tid + st];
            red[tid + BLOCK]     += red[tid + BLOCK + st];
            red[tid + 2 * BLOCK] += red[tid + 2 * BLOCK + st];
        }
        __syncthreads();
    }
    const float inv = 1.0f / (float)V;
    const float mx = red[0] * inv, my = red[BLOCK] * inv, mz = red[2 * BLOCK] * inv;

    for (int v = tid; v < V; v += BLOCK) {
        const float* vp = verts + ((size_t)tile * V + v) * 3;
        lv[v] = make_float4(vp[0] - mx, vp[1] - my, vp[2] - mz, 0.f);
    }
    __syncthreads();

    // ---- small outputs ----
    if (s == 0) {
        for (int v = tid; v < V; v += BLOCK) {
            float4 q = lv[v];
            size_t o = offLV + ((size_t)tile * V + v) * 3;
            out[o + 0] = q.x;
            out[o + 1] = q.y;
            out[o + 2] = q.z;
        }
        if (tid == 0) {
            size_t mo = offMV + (size_t)tile * 3;
            out[mo + 0] = mx;
            out[mo + 1] = my;
            out[mo + 2] = mz;
        }
    }
    if (blockIdx.x == 0) {
        for (int i = tid; i < D * 3; i += BLOCK)
            out[offDIR + i] = dirs[i];
        if (tid < 2) out[offZ + tid] = 0.f;
    }

    const int d = s * BLOCK + tid;
    if (d >= D) return;

    const float dx = dirs[d * 3 + 0];
    const float dy = dirs[d * 3 + 1];
    const float dz = dirs[d * 3 + 2];
    const float pv = smooth[tile];

    // ---- pass A (fused 1+2): zmax + speculative sum with k=1 ----
    float zmax = 0.f, sum = 0.f;
    #pragma unroll 4
    for (int v = 0; v < V; ++v) {
        float4 q = lv[v];
        float z = fmaf(q.x, dx, fmaf(q.y, dy, q.z * dz));
        zmax = fmaxf(zmax, z);
        float w = fminf(fmaxf(fast_exp2(pv * fast_log2(z)), LBv), UBv); // z<=0 -> NaN/0, masked:
        sum += (z > 0.f) ? w : 0.f;
    }

    // ---- k rescue (requires zmax^p < 1e-20; statistically never taken) ----
    float kk = 1.f, lk2 = 0.f;               // k, log2(k)
    if (zmax > 0.f) {
        float e10 = fast_log2(zmax) * LOG10_2 * pv;     // log10(zmax)*p
        if (e10 < -20.f) {
            float n = ceilf((-20.f - e10) / pv);
            lk2 = n * LOG2_10;
            kk  = fast_exp2(lk2);
            sum = 0.f;
            for (int v = 0; v < V; ++v) {
                float4 q = lv[v];
                float z = fmaf(q.x, dx, fmaf(q.y, dy, q.z * dz));
                float zms = fmaxf(z, 0.f) * kk;
                float w = fminf(fmaxf(fast_exp2(pv * fast_log2(zms)), LBv), UBv);
                sum += (zms > 0.f) ? w : 0.f;
            }
        }
    }

    // h = clip(sum^(1/p), LB, UB); sum==0 -> 0 -> clipped to LB
    float h = (sum > 0.f)
        ? fminf(fmaxf(fast_exp2(fast_log2(sum) * (1.f / pv)), LBv), UBv)
        : LBv;

    // ---- pass B: surf accumulate; dhdz = (z*k/h)^(p-1) = exp2(c1*log2(z)+c0) ----
    const float c1 = pv - 1.f;
    const float c0 = c1 * (lk2 - fast_log2(h));
    float ax = 0.f, ay = 0.f, az = 0.f;
    #pragma unroll 4
    for (int v = 0; v < V; ++v) {
        float4 q = lv[v];
        float z = fmaf(q.x, dx, fmaf(q.y, dy, q.z * dz));
        float l = fast_log2(z);                                  // z<=0 -> NaN/-inf, masked:
        float w = fminf(fmaxf(fast_exp2(fmaf(c1, l, c0)), LBv), UBv);
        w = (z > 0.f) ? w : LBv;                                 // ref: dhdz=LB for ratio<=0
        ax = fmaf(w, q.x, ax);
        ay = fmaf(w, q.y, ay);
        az = fmaf(w, q.z, az);
    }

    size_t po = ((size_t)tile * D + d) * 3;
    out[po + 0] = ax + mx;
    out[po + 1] = ay + my;
    out[po + 2] = az + mz;

    float hout = h / kk;
    size_t dho = offDH + ((size_t)tile * D + d) * 4;
    out[dho + 0] = dx;
    out[dho + 1] = dy;
    out[dho + 2] = dz;
    out[dho + 3] = hout;
}

extern "C" void kernel_launch(void* const* d_in, const int* in_sizes, int n_in,
                              void* d_out, int out_size, void* d_ws, size_t ws_size,
                              hipStream_t stream) {
    const float* verts  = (const float*)d_in[0];
    const float* smooth = (const float*)d_in[1];
    const float* dirs   = (const float*)d_in[2];
    float* out = (float*)d_out;

    // verts = NT*V*3, smooth = NT, dirs = D*3
    const int NT = in_sizes[1];
    const int D  = in_sizes[2] / 3;
    const int V  = in_sizes[0] / (3 * NT);
    const int SPLIT = (D + BLOCK - 1) / BLOCK;

    const size_t offDH  = (size_t)NT * D * 3;            // after points
    const size_t offMV  = offDH  + (size_t)NT * D * 4;   // after direction_h
    const size_t offDIR = offMV  + (size_t)NT * 3;       // after mean_v
    const size_t offLV  = offDIR + (size_t)D * 3;        // after directions
    const size_t offZ   = offLV  + (size_t)NT * V * 3;   // after local_vertices

    const size_t shmem = (4 * (size_t)V + 3 * BLOCK) * sizeof(float);

    dim3 grid(NT * SPLIT);
    dim3 block(BLOCK);
    hipLaunchKernelGGL(mcnet_fast, grid, block, shmem, stream,
                       verts, smooth, dirs, out,
                       NT, V, D, SPLIT, offDH, offMV, offDIR, offLV, offZ);
}

// Round 8
// 92.903 us; speedup vs baseline: 7.5821x; 1.2506x over previous
//
#include <hip/hip_runtime.h>
#include <math.h>

#define BLOCK 256
#define LBv 1e-20f
#define UBv 1e20f
#define LOG10_2 0.3010299956639812f

// Raw HW transcendentals: v_log_f32 / v_exp_f32 (~1 ulp).
// Edge semantics used deliberately: log2(0) = -inf, exp2(-inf) = 0.
#if __has_builtin(__builtin_amdgcn_logf) && __has_builtin(__builtin_amdgcn_exp2f)
__device__ __forceinline__ float fast_log2(float x) { return __builtin_amdgcn_logf(x); }
__device__ __forceinline__ float fast_exp2(float x) { return __builtin_amdgcn_exp2f(x); }
#else
__device__ __forceinline__ float fast_log2(float x) { return log2f(x); }
__device__ __forceinline__ float fast_exp2(float x) { return exp2f(x); }
#endif

__global__ __launch_bounds__(BLOCK) void mcnet_fused(
    const float* __restrict__ verts,   // (NT, V, 3) f32
    const float* __restrict__ smooth,  // (NT,)      f32
    const float* __restrict__ dirs,    // (D, 3)     f32
    float* __restrict__ out,           // f32, chunks concatenated flat
    int NT, int V, int D, int SPLIT,
    size_t offDH, size_t offMV, size_t offDIR, size_t offLV, size_t offZ)
{
    extern __shared__ float smem[];            // [4*V] lv (float4) + [3*BLOCK] reduce
    float4* lv = (float4*)smem;
    float*  red = smem + 4 * (size_t)V;

    const int tid  = threadIdx.x;
    const int tile = blockIdx.x / SPLIT;
    const int s    = blockIdx.x % SPLIT;

    // ---- mean via LDS tree reduction ----
    float sx = 0.f, sy = 0.f, sz = 0.f;
    for (int v = tid; v < V; v += BLOCK) {
        const float* vp = verts + ((size_t)tile * V + v) * 3;
        sx += vp[0]; sy += vp[1]; sz += vp[2];
    }
    red[tid] = sx; red[tid + BLOCK] = sy; red[tid + 2 * BLOCK] = sz;
    __syncthreads();
    for (int st = BLOCK / 2; st > 0; st >>= 1) {
        if (tid < st) {
            red[tid]             += red[tid + st];
            red[tid + BLOCK]     += red[tid + BLOCK + st];
            red[tid + 2 * BLOCK] += red[tid + 2 * BLOCK + st];
        }
        __syncthreads();
    }
    const float inv = 1.0f / (float)V;
    const float mx = red[0] * inv, my = red[BLOCK] * inv, mz = red[2 * BLOCK] * inv;

    for (int v = tid; v < V; v += BLOCK) {
        const float* vp = verts + ((size_t)tile * V + v) * 3;
        lv[v] = make_float4(vp[0] - mx, vp[1] - my, vp[2] - mz, 0.f);
    }
    __syncthreads();

    // ---- small outputs ----
    if (s == 0) {
        for (int v = tid; v < V; v += BLOCK) {
            float4 q = lv[v];
            size_t o = offLV + ((size_t)tile * V + v) * 3;
            out[o + 0] = q.x;
            out[o + 1] = q.y;
            out[o + 2] = q.z;
        }
        if (tid == 0) {
            size_t mo = offMV + (size_t)tile * 3;
            out[mo + 0] = mx;
            out[mo + 1] = my;
            out[mo + 2] = mz;
        }
    }
    if (blockIdx.x == 0) {
        for (int i = tid; i < D * 3; i += BLOCK)
            out[offDIR + i] = dirs[i];
        if (tid < 2) out[offZ + tid] = 0.f;
    }

    const int d = s * BLOCK + tid;
    if (d >= D) return;

    const float dx = dirs[d * 3 + 0];
    const float dy = dirs[d * 3 + 1];
    const float dz = dirs[d * 3 + 2];
    const float pv = smooth[tile];
    const float c1 = pv - 1.f;

    // ---- single fused pass: S = sum min(z^p,UB);  vec = sum z^(p-1)*lv ----
    // zc=max(z,0): log2(0)=-inf -> exp2=0 masks z<=0 lanes branchlessly.
    // z^p = z^(p-1)*z saves one exp2.
    float zmax = 0.f, S = 0.f;
    float ax = 0.f, ay = 0.f, az = 0.f;
    #pragma unroll 8
    for (int v = 0; v < V; ++v) {
        float4 q = lv[v];
        float z  = fmaf(q.x, dx, fmaf(q.y, dy, q.z * dz));
        float zc = fmaxf(z, 0.f);
        zmax = fmaxf(zmax, zc);
        float l = fast_log2(zc);          // -inf at zc==0
        float w = fast_exp2(c1 * l);      // z^(p-1), 0 at zc==0
        float u = w * zc;                 // z^p
        S += fminf(u, UBv);
        ax = fmaf(w, q.x, ax);
        ay = fmaf(w, q.y, ay);
        az = fmaf(w, q.z, az);
    }

    // fast path valid iff zmax^p >= 1e-10 (no k-rescale, LB floors negligible,
    // scale exponent |-(p-1)/p*log2 S| < 75 -> exp2 in range).
    if (zmax > 0.f && pv * (fast_log2(zmax) * LOG10_2) >= -10.f) {
        float h = fminf(fmaxf(fast_exp2(fast_log2(S) * (1.f / pv)), LBv), UBv);
        float scale = fast_exp2(-c1 * fast_log2(h));   // h^-(p-1)

        size_t po = ((size_t)tile * D + d) * 3;
        out[po + 0] = fmaf(ax, scale, mx);
        out[po + 1] = fmaf(ay, scale, my);
        out[po + 2] = fmaf(az, scale, mz);

        size_t dho = offDH + ((size_t)tile * D + d) * 4;
        out[dho + 0] = dx;
        out[dho + 1] = dy;
        out[dho + 2] = dz;
        out[dho + 3] = h;                               // k == 1
    } else {
        // ---- literal fallback (k-rescale / degenerate; never taken for
        // the bench data distribution) — exact reference semantics ----
        float zm_log   = (zmax > 0.f) ? log10f(zmax) : -INFINITY;
        float exponent = zm_log * pv;
        float lk = (exponent < -20.f) ? (-20.f - exponent) / pv : 0.f;
        float kk = powf(10.f, fminf(fmaxf(ceilf(lk), 0.f), UBv));

        float sum = 0.f;
        for (int v = 0; v < V; ++v) {
            float4 q = lv[v];
            float z   = fmaf(q.x, dx, fmaf(q.y, dy, q.z * dz));
            float zms = fmaxf(z, 0.f) * kk;
            float w   = (zms > 0.f) ? fminf(fmaxf(powf(zms, pv), LBv), UBv) : 0.f;
            sum += w;
        }
        float h = fminf(fmaxf(powf(sum, 1.f / pv), LBv), UBv);

        float bx = 0.f, by = 0.f, bz = 0.f;
        for (int v = 0; v < V; ++v) {
            float4 q = lv[v];
            float z     = fmaf(q.x, dx, fmaf(q.y, dy, q.z * dz));
            float zms   = fmaxf(z, 0.f) * kk;
            float ratio = zms / h;
            float w = (ratio > 0.f) ? fminf(fmaxf(powf(ratio, c1), LBv), UBv) : LBv;
            bx = fmaf(w, q.x, bx);
            by = fmaf(w, q.y, by);
            bz = fmaf(w, q.z, bz);
        }

        size_t po = ((size_t)tile * D + d) * 3;
        out[po + 0] = bx + mx;
        out[po + 1] = by + my;
        out[po + 2] = bz + mz;

        size_t dho = offDH + ((size_t)tile * D + d) * 4;
        out[dho + 0] = dx;
        out[dho + 1] = dy;
        out[dho + 2] = dz;
        out[dho + 3] = h / kk;
    }
}

extern "C" void kernel_launch(void* const* d_in, const int* in_sizes, int n_in,
                              void* d_out, int out_size, void* d_ws, size_t ws_size,
                              hipStream_t stream) {
    const float* verts  = (const float*)d_in[0];
    const float* smooth = (const float*)d_in[1];
    const float* dirs   = (const float*)d_in[2];
    float* out = (float*)d_out;

    // verts = NT*V*3, smooth = NT, dirs = D*3
    const int NT = in_sizes[1];
    const int D  = in_sizes[2] / 3;
    const int V  = in_sizes[0] / (3 * NT);
    const int SPLIT = (D + BLOCK - 1) / BLOCK;

    const size_t offDH  = (size_t)NT * D * 3;            // after points
    const size_t offMV  = offDH  + (size_t)NT * D * 4;   // after direction_h
    const size_t offDIR = offMV  + (size_t)NT * 3;       // after mean_v
    const size_t offLV  = offDIR + (size_t)D * 3;        // after directions
    const size_t offZ   = offLV  + (size_t)NT * V * 3;   // after local_vertices

    const size_t shmem = (4 * (size_t)V + 3 * BLOCK) * sizeof(float);

    dim3 grid(NT * SPLIT);
    dim3 block(BLOCK);
    hipLaunchKernelGGL(mcnet_fused, grid, block, shmem, stream,
                       verts, smooth, dirs, out,
                       NT, V, D, SPLIT, offDH, offMV, offDIR, offLV, offZ);
}